// Round 6
// baseline (351.568 us; speedup 1.0000x reference)
//
#include <hip/hip_runtime.h>

#define NB 32
#define NT 2048
#define ND 1024
#define NU 1024
#define NM (NB*NT)   // 65536 rows

using f32x4 = __attribute__((ext_vector_type(4))) float;
using s16x8 = __attribute__((ext_vector_type(8))) short;

#define BAR()   asm volatile("s_barrier" ::: "memory")
#define LGKM0() asm volatile("s_waitcnt lgkmcnt(0)" ::: "memory")
#define VMC(n)  asm volatile("s_waitcnt vmcnt(" #n ")" ::: "memory")
#define SB0()   __builtin_amdgcn_sched_barrier(0)

__device__ __forceinline__ unsigned short f2bf(float f) {
  unsigned u = __builtin_bit_cast(unsigned, f);
  u = u + 0x7fffu + ((u >> 16) & 1u);   // round-to-nearest-even
  return (unsigned short)(u >> 16);
}

__device__ __forceinline__ void gload_lds16(const void* g, void* l) {
  __builtin_amdgcn_global_load_lds(
      (const __attribute__((address_space(1))) unsigned int*)g,
      (__attribute__((address_space(3))) unsigned int*)l, 16, 0, 0);
}

__device__ __forceinline__ float tanh_fast(float x) {
  float e = __expf(2.0f * x);
  return 1.0f - 2.0f * __builtin_amdgcn_rcpf(e + 1.0f);
}

// ---- BK=32 tile staging: one 256x32 bf16 tile (16KB) per call, 2 gloads/wave.
// LDS linear dest; global source chunk pre-swizzled: LDS[row][c] = G[row][c ^ ((row>>1)&3)]
__device__ __forceinline__ void stage_tile(const unsigned short* g, unsigned short* l,
                                           int w, int lane) {
  int l2 = lane >> 2;
  int gc = (lane & 3) ^ ((lane >> 3) & 3);   // (l2>>1)&3 folded
#pragma unroll
  for (int i = 0; i < 2; ++i) {
    int rblk = w * 2 + i;                    // 16-row block
    int row = rblk * 16 + l2;
    gload_lds16(g + (size_t)row * 1024 + gc * 8, l + rblk * 512);
  }
}

// fragment read: 16B at (row, k-chunk lg), chunk XOR-swizzled by (row>>1)&3
__device__ __forceinline__ s16x8 frag_read(const unsigned short* buf, int row, int lg) {
  int cr = lg ^ ((row >> 1) & 3);
  return *(const s16x8*)(buf + row * 32 + cr * 8);
}

#define MFMA16(MB, FA) \
  _Pragma("unroll") \
  for (int m = 0; m < 4; ++m) { \
    _Pragma("unroll") \
    for (int n = 0; n < 4; ++n) \
      acc[(MB) + m][n] = __builtin_amdgcn_mfma_f32_16x16x32_bf16( \
          FA[m], fb[n], acc[(MB) + m][n], 0, 0, 0); \
  }

// K-tile = 2 phases. ph1: MFMA m0-3 | read fa47(T) | stage A(T+3) | VMC | BAR
//           ph2: MFMA m4-7 | pre-read fa03/fb(T+1) | stage B(T+3) | BAR
template<bool PRE, bool ST, int VM>
__device__ __forceinline__ void tile_body(
    int kt, const unsigned short* gA, const unsigned short* gB,
    unsigned short* sA, unsigned short* sB, f32x4 (&acc)[8][4],
    s16x8 (&fa03)[4], s16x8 (&fa47)[4], s16x8 (&fb)[4],
    int w, int lane, int wr, int wc, int l15, int lg) {
  const unsigned short* pA = sA + (kt & 3) * 8192;
  const unsigned short* qA = sA + ((kt + 1) & 3) * 8192;
  const unsigned short* qB = sB + ((kt + 1) & 3) * 8192;
  unsigned short* stA = sA + ((kt + 3) & 3) * 8192;
  unsigned short* stB = sB + ((kt + 3) & 3) * 8192;
  // ---------- ph1
  LGKM0(); SB0();
  __builtin_amdgcn_s_setprio(1);
  MFMA16(0, fa03);
  __builtin_amdgcn_s_setprio(0);
  SB0();
#pragma unroll
  for (int i = 0; i < 4; ++i)
    fa47[i] = frag_read(pA, wr * 128 + (4 + i) * 16 + l15, lg);
  if (ST) stage_tile(gA + (size_t)(kt + 3) * 32, stA, w, lane);
  if constexpr (VM == 6) { VMC(6); }
  else if constexpr (VM == 4) { VMC(4); }
  else if constexpr (VM == 0) { VMC(0); }
  BAR();
  // ---------- ph2
  LGKM0(); SB0();
  __builtin_amdgcn_s_setprio(1);
  MFMA16(4, fa47);
  __builtin_amdgcn_s_setprio(0);
  SB0();
  if (PRE) {
#pragma unroll
    for (int i = 0; i < 4; ++i)
      fa03[i] = frag_read(qA, wr * 128 + i * 16 + l15, lg);
#pragma unroll
    for (int n = 0; n < 4; ++n)
      fb[n] = frag_read(qB, wc * 64 + n * 16 + l15, lg);
  }
  if (ST) stage_tile(gB + (size_t)(kt + 3) * 32, stB, w, lane);
  BAR();
}

// 256x256 tile, BK=32, quad-buffered, spread reads + 1-phase pre-read.
__global__ __launch_bounds__(512, 2) void k_score_gemm32(
    const unsigned short* __restrict__ vbf, const unsigned short* __restrict__ W2t,
    const float* __restrict__ add2, const float* __restrict__ Vk,
    float* __restrict__ score_part) {
  __shared__ unsigned short sA[32768];   // 4 bufs x 256 x 32
  __shared__ unsigned short sB[32768];
  const int tid = threadIdx.x;
  const int w = tid >> 6, lane = tid & 63;
  const int wr = w >> 2, wc = w & 3;             // 2M x 4N waves
  const int l15 = lane & 15, lg = lane >> 4;

  // XCD-contiguous: co-resident blocks on one XCD share the A strip via L2
  const int L = blockIdx.x;
  const int g = (L & 7) * 128 + (L >> 3);
  const int mtile = g >> 2, ntile = g & 3;

  const unsigned short* gA = vbf + ((size_t)mtile << 18);
  const unsigned short* gB = W2t + ((size_t)ntile << 18);

  f32x4 acc[8][4] = {};
  s16x8 fa03[4], fa47[4], fb[4];

  // Prologue: stage tiles 0,1,2 (A+B interleaved), drain tile0, preload frags.
  stage_tile(gA, sA, w, lane);              stage_tile(gB, sB, w, lane);
  stage_tile(gA + 32, sA + 8192, w, lane);  stage_tile(gB + 32, sB + 8192, w, lane);
  stage_tile(gA + 64, sA + 16384, w, lane); stage_tile(gB + 64, sB + 16384, w, lane);
  VMC(8);   // drain A(0),B(0)
  BAR();
#pragma unroll
  for (int i = 0; i < 4; ++i) fa03[i] = frag_read(sA, wr * 128 + i * 16 + l15, lg);
#pragma unroll
  for (int n = 0; n < 4; ++n) fb[n] = frag_read(sB, wc * 64 + n * 16 + l15, lg);

#pragma unroll 1
  for (int kt = 0; kt < 29; ++kt)
    tile_body<true, true, 6>(kt, gA, gB, sA, sB, acc, fa03, fa47, fb, w, lane, wr, wc, l15, lg);
  tile_body<true, false, 4>(29, gA, gB, sA, sB, acc, fa03, fa47, fb, w, lane, wr, wc, l15, lg);
  tile_body<true, false, 0>(30, gA, gB, sA, sB, acc, fa03, fa47, fb, w, lane, wr, wc, l15, lg);
  tile_body<false, false, -1>(31, gA, gB, sA, sB, acc, fa03, fa47, fb, w, lane, wr, wc, l15, lg);

  // Epilogue: x = acc + add2[b][u]; row-sum of tanh(x)*Vk[u] over this 256-col slab
  const int b = (mtile * 256) >> 11;   // block-uniform
  float vks[4], adds[4];
#pragma unroll
  for (int n = 0; n < 4; ++n) {
    int u = ntile * 256 + wc * 64 + n * 16 + l15;
    vks[n] = Vk[u];
    adds[n] = add2[(b << 10) + u];
  }
  __syncthreads();
  float* part = (float*)sA;   // [4][256]
#pragma unroll
  for (int m = 0; m < 8; ++m) {
#pragma unroll
    for (int j = 0; j < 4; ++j) {
      float s = 0.f;
#pragma unroll
      for (int n = 0; n < 4; ++n) {
        float x = acc[m][n][j] + adds[n];
        s = fmaf(tanh_fast(x), vks[n], s);
      }
#pragma unroll
      for (int off = 1; off < 16; off <<= 1) s += __shfl_xor(s, off);
      if (l15 == 0) part[wc * 256 + wr * 128 + m * 16 + lg * 4 + j] = s;
    }
  }
  __syncthreads();
  if (tid < 256) {
    float v = part[tid] + part[256 + tid] + part[512 + tid] + part[768 + tid];
    score_part[((size_t)ntile << 16) + mtile * 256 + tid] = v;
  }
}

// add2[b][u] = query[b]·W1_k[:,u] + W1_b[u] + W2_b[u]
__global__ void k_qproj(const float* __restrict__ q, const float* __restrict__ W1,
                        const float* __restrict__ W1b, const float* __restrict__ W2b,
                        float* __restrict__ add2) {
  int u = blockIdx.x * 256 + threadIdx.x;
  int b = blockIdx.y;
  const float* qr = q + (b << 10);
  float s = 0.f;
#pragma unroll 8
  for (int d = 0; d < ND; ++d) s = fmaf(qr[d], W1[d * NU + u], s);
  add2[(b << 10) + u] = s + W1b[u] + W2b[u];
}

// W2_k [D][U] f32 -> W2t [U][D] bf16
__global__ void k_w2t(const float* __restrict__ W2, unsigned short* __restrict__ W2t) {
  __shared__ unsigned short tile[64][65];
  int bu = blockIdx.x * 64, bd = blockIdx.y * 64;
  int x = threadIdx.x & 63, y4 = threadIdx.x >> 6;
#pragma unroll
  for (int r = 0; r < 16; ++r) {
    int dl = y4 * 16 + r;
    tile[x][dl] = f2bf(W2[(size_t)(bd + dl) * NU + bu + x]);
  }
  __syncthreads();
#pragma unroll
  for (int r = 0; r < 16; ++r) {
    int ul = y4 * 16 + r;
    W2t[(size_t)(bu + ul) * ND + bd + x] = tile[ul][x];
  }
}

// values f32 -> bf16
__global__ void k_cvt_values(const float4* __restrict__ v, ushort4* __restrict__ o) {
  const int n4 = NM * ND / 4;
  for (int i = blockIdx.x * blockDim.x + threadIdx.x; i < n4; i += gridDim.x * blockDim.x) {
    float4 f = v[i];
    ushort4 h;
    h.x = f2bf(f.x); h.y = f2bf(f.y); h.z = f2bf(f.z); h.w = f2bf(f.w);
    o[i] = h;
  }
}

// ---- Fallback (small ws): 128^2 reg-staged fused GEMM (8 partials) ----
__global__ __launch_bounds__(256) void k_score_gemm_small(
    const float* __restrict__ values, const unsigned short* __restrict__ W2t,
    const float* __restrict__ add2, const float* __restrict__ Vk,
    float* __restrict__ score_part) {
  __shared__ unsigned short sA[128 * 64];
  __shared__ unsigned short sB[128 * 64];
  const int tid = threadIdx.x;
  const int w = tid >> 6, lane = tid & 63;
  const int wr = w >> 1, wc = w & 1;
  const int l15 = lane & 15, lg = lane >> 4;
  const int r8 = lane >> 3, c8 = lane & 7;
  const int cs8 = c8 ^ r8;
  const int L = blockIdx.x;
  const int mtile = (L & 7) * 64 + ((L >> 3) >> 3);
  const int ntile = (L >> 3) & 7;
  f32x4 acc[4][4] = {};
  for (int kk = 0; kk < 16; ++kk) {
    const int k0 = kk * 64;
#pragma unroll
    for (int i = 0; i < 4; ++i) {
      int nl = (w * 4 + i) * 8 + r8;
      gload_lds16(W2t + ((size_t)(ntile * 128 + nl) << 10) + k0 + cs8 * 8, sB + (w * 4 + i) * 512);
    }
#pragma unroll
    for (int i = 0; i < 8; ++i) {
      int idx = tid + (i << 8);
      int row = idx >> 4, kc = idx & 15;
      const float4 f = *(const float4*)(values + ((size_t)(mtile * 128 + row) << 10) + k0 + kc * 4);
      ushort4 h;
      h.x = f2bf(f.x); h.y = f2bf(f.y); h.z = f2bf(f.z); h.w = f2bf(f.w);
      int cc = (kc >> 1) ^ (row & 7);
      *(ushort4*)(sA + (row << 6) + cc * 8 + (kc & 1) * 4) = h;
    }
    __syncthreads();
#pragma unroll
    for (int ks = 0; ks < 2; ++ks) {
      s16x8 af[4], bfr[4];
#pragma unroll
      for (int m = 0; m < 4; ++m) {
        int row = wr * 64 + m * 16 + l15;
        int cc = (ks * 4 + lg) ^ (l15 & 7);
        af[m] = *(const s16x8*)(sA + (row << 6) + cc * 8);
      }
#pragma unroll
      for (int n = 0; n < 4; ++n) {
        int row = wc * 64 + n * 16 + l15;
        int cc = (ks * 4 + lg) ^ (l15 & 7);
        bfr[n] = *(const s16x8*)(sB + (row << 6) + cc * 8);
      }
#pragma unroll
      for (int m = 0; m < 4; ++m)
#pragma unroll
        for (int n = 0; n < 4; ++n)
          acc[m][n] = __builtin_amdgcn_mfma_f32_16x16x32_bf16(af[m], bfr[n], acc[m][n], 0, 0, 0);
    }
    __syncthreads();
  }
  const int b = (mtile * 128) >> 11;
  float vks[4], adds[4];
#pragma unroll
  for (int n = 0; n < 4; ++n) {
    int u = ntile * 128 + wc * 64 + n * 16 + l15;
    vks[n] = Vk[u];
    adds[n] = add2[(b << 10) + u];
  }
  float rs[4][4];
#pragma unroll
  for (int m = 0; m < 4; ++m)
#pragma unroll
    for (int j = 0; j < 4; ++j) {
      float s = 0.f;
#pragma unroll
      for (int n = 0; n < 4; ++n) {
        float x = acc[m][n][j] + adds[n];
        s = fmaf(tanh_fast(x), vks[n], s);
      }
#pragma unroll
      for (int off = 1; off < 16; off <<= 1) s += __shfl_xor(s, off);
      rs[m][j] = s;
    }
  __syncthreads();
  float* rowsum = (float*)sA;
  if (wc == 0 && l15 == 0)
#pragma unroll
    for (int m = 0; m < 4; ++m)
#pragma unroll
      for (int j = 0; j < 4; ++j) rowsum[wr * 64 + m * 16 + lg * 4 + j] = rs[m][j];
  __syncthreads();
  if (wc == 1 && l15 == 0)
#pragma unroll
    for (int m = 0; m < 4; ++m)
#pragma unroll
      for (int j = 0; j < 4; ++j) rowsum[wr * 64 + m * 16 + lg * 4 + j] += rs[m][j];
  __syncthreads();
  if (tid < 128)
    score_part[((size_t)ntile << 16) + mtile * 128 + tid] = rowsum[tid];
}

// softmax over T per batch; sums npart N-tile partials first (deterministic)
__global__ void k_softmax(const float* __restrict__ sp, float* __restrict__ w, int npart) {
  __shared__ float redm[4], reds[4];
  int b = blockIdx.x, tid = threadIdx.x;
  float s[8];
  float mx = -1e30f;
#pragma unroll
  for (int i = 0; i < 8; ++i) {
    int t = i * 256 + tid;
    float v = 0.f;
    for (int p = 0; p < npart; ++p) v += sp[((size_t)p << 16) + (b << 11) + t];
    s[i] = v;
    mx = fmaxf(mx, v);
  }
#pragma unroll
  for (int o = 1; o < 64; o <<= 1) mx = fmaxf(mx, __shfl_xor(mx, o));
  if ((tid & 63) == 0) redm[tid >> 6] = mx;
  __syncthreads();
  mx = fmaxf(fmaxf(redm[0], redm[1]), fmaxf(redm[2], redm[3]));
  float sum = 0.f;
#pragma unroll
  for (int i = 0; i < 8; ++i) { s[i] = __expf(s[i] - mx); sum += s[i]; }
#pragma unroll
  for (int o = 1; o < 64; o <<= 1) sum += __shfl_xor(sum, o);
  if ((tid & 63) == 0) reds[tid >> 6] = sum;
  __syncthreads();
  float inv = 1.0f / (reds[0] + reds[1] + reds[2] + reds[3]);
#pragma unroll
  for (int i = 0; i < 8; ++i) w[(b << 11) + i * 256 + tid] = s[i] * inv;
}

// context partials: part[tc][b][d] = sum_{t in chunk} w[b][t]*values[b][t][d] (float4)
__global__ void k_context(const float* __restrict__ values, const float* __restrict__ wv,
                          float* __restrict__ part) {
  int d4 = threadIdx.x;
  int b = blockIdx.y, tc = blockIdx.z;
  const float4* vb = (const float4*)(values + ((size_t)b << 21) + ((size_t)tc << 18)) + d4;
  const float* wb = wv + (b << 11) + (tc << 8);
  float ax = 0.f, ay = 0.f, az = 0.f, aw = 0.f;
#pragma unroll 4
  for (int t = 0; t < 256; ++t) {
    float4 v = vb[(size_t)t << 8];
    float wt = wb[t];
    ax = fmaf(wt, v.x, ax); ay = fmaf(wt, v.y, ay);
    az = fmaf(wt, v.z, az); aw = fmaf(wt, v.w, aw);
  }
  float4* po = (float4*)(part + (((size_t)tc * NB + b) << 10)) + d4;
  *po = make_float4(ax, ay, az, aw);
}

__global__ void k_ctx_reduce(const float* __restrict__ part, float* __restrict__ out) {
  int i = blockIdx.x * 256 + threadIdx.x;  // 32768
  float s = 0.f;
#pragma unroll
  for (int p = 0; p < 8; ++p) s += part[(p << 15) + i];
  out[i] = s;
}

extern "C" void kernel_launch(void* const* d_in, const int* in_sizes, int n_in,
                              void* d_out, int out_size, void* d_ws, size_t ws_size,
                              hipStream_t stream) {
  const float* query  = (const float*)d_in[0];
  const float* values = (const float*)d_in[1];
  const float* W1k    = (const float*)d_in[2];
  const float* W1b    = (const float*)d_in[3];
  const float* W2k    = (const float*)d_in[4];
  const float* W2b    = (const float*)d_in[5];
  const float* Vk     = (const float*)d_in[6];
  // V_b dropped: softmax is shift-invariant.
  float* out = (float*)d_out;
  char* ws = (char*)d_ws;

  size_t off = 0;
  float* add2 = (float*)(ws + off); off += (size_t)NB * NU * 4;          // 128 KB
  float* sp   = (float*)(ws + off); off += (size_t)8 * NM * 4;           // 2 MB
  float* wv   = (float*)(ws + off); off += (size_t)NM * 4;               // 256 KB
  float* ctxp = (float*)(ws + off); off += (size_t)8 * NB * ND * 4;      // 1 MB
  unsigned short* W2t = (unsigned short*)(ws + off); off += (size_t)NU * ND * 2; // 2 MB
  unsigned short* vbf = (unsigned short*)(ws + off);
  size_t need_big = off + (size_t)NM * ND * 2;                           // +128 MB
  bool big = ws_size >= need_big;

  k_qproj<<<dim3(4, 32), 256, 0, stream>>>(query, W1k, W1b, W2b, add2);
  k_w2t<<<dim3(16, 16), 256, 0, stream>>>(W2k, W2t);
  if (big) {
    k_cvt_values<<<dim3(2048), 256, 0, stream>>>((const float4*)values, (ushort4*)vbf);
    k_score_gemm32<<<dim3(1024), 512, 0, stream>>>(vbf, W2t, add2, Vk, sp);
    k_softmax<<<dim3(32), 256, 0, stream>>>(sp, wv, 4);
  } else {
    k_score_gemm_small<<<dim3(4096), 256, 0, stream>>>(values, W2t, add2, Vk, sp);
    k_softmax<<<dim3(32), 256, 0, stream>>>(sp, wv, 8);
  }
  k_context<<<dim3(1, 32, 8), 256, 0, stream>>>(values, wv, ctxp);
  k_ctx_reduce<<<dim3(128), 256, 0, stream>>>(ctxp, out);
}